// Round 21
// baseline (139.966 us; speedup 1.0000x reference)
//
#include <hip/hip_runtime.h>
#include <stdint.h>

typedef __attribute__((ext_vector_type(8))) short short8;
typedef __attribute__((ext_vector_type(4))) float floatx4;
typedef __attribute__((ext_vector_type(16))) float f32x16;
typedef __attribute__((ext_vector_type(4))) unsigned int uint4v;
typedef __attribute__((ext_vector_type(2))) unsigned int uint2v;

#define NSEQ 8
#define BLKSZ 16
#define NBLK_PER_SEQ 128
#define HQN 32
#define HKVN 8
#define GQ 4
#define HD 128
#define WINDOW 1024
// SCALE * log2(e): softmax in exp2 domain
#define QSCALE 0.12751744f

#define QB 32       // q rows per wave (32x32 MFMA)
#define KVB 32      // kv tile (K and V both double-buffered)
#define KROW 136    // K lds row stride (bf16)
#define VROW 40     // V^T lds row stride

#define MFMA32 __builtin_amdgcn_mfma_f32_32x32x16_bf16

// two f32 -> packed bf16x2 (round-half-up); low16 = lo, high16 = hi
static __device__ __forceinline__ unsigned int pack2bf(float lo, float hi) {
    unsigned int a = __builtin_bit_cast(unsigned int, lo) + 0x8000u;
    unsigned int b = __builtin_bit_cast(unsigned int, hi) + 0x8000u;
    return __builtin_amdgcn_perm(b, a, 0x07060302u);
}

static __device__ __forceinline__ float xhalf_max(float x) {
    return fmaxf(x, __shfl_xor(x, 32));
}

__global__ __launch_bounds__(128, 2)
void attn_fwd(const float* __restrict__ qg,
              const float* __restrict__ kg,
              const float* __restrict__ vg,
              const int* __restrict__ bt,
              const int* __restrict__ seqlens,
              const int* __restrict__ qsl,
              float* __restrict__ outg)
{
    __shared__ __align__(16) short Klds[2][KVB][KROW];  // 17408 B
    __shared__ __align__(16) short Vt[2][HD][VROW];     // 20480 B -> 37888 total

    const int tid  = threadIdx.x;
    const int lane = tid & 63;
    const int wave = tid >> 6;        // 0/1
    const int l31  = lane & 31;
    const int hi   = lane >> 5;

    // XCD pinning: b&7 = kv head; hp selects which head-pair of the GQA group
    const int b  = blockIdx.x;
    const int h  = b & 7;
    const int qt = (b >> 3) & 7;
    const int hp = (b >> 6) & 1;
    const int s  = b >> 7;
    const int q0 = qt * QB;

    const int qstart = qsl[s];
    const int numq   = qsl[s + 1] - qstart;
    const int slen   = seqlens[s];
    const int ctx    = slen - numq;
    const int hq     = h * GQ + hp * 2 + wave;

    // ---- Q fragments (B-operand 32x32x16: col=q=l31, k=ks*16+hi*8+j), pre-scaled ----
    short8 qf[8];
    {
        const float* qrow = qg + ((size_t)(qstart + q0 + l31) * HQN + hq) * HD;
        #pragma unroll
        for (int ks = 0; ks < 8; ++ks) {
            floatx4 f0 = *(const floatx4*)(qrow + ks * 16 + hi * 8);
            floatx4 f1 = *(const floatx4*)(qrow + ks * 16 + hi * 8 + 4);
            uint4v w;
            w[0] = pack2bf(f0[0] * QSCALE, f0[1] * QSCALE);
            w[1] = pack2bf(f0[2] * QSCALE, f0[3] * QSCALE);
            w[2] = pack2bf(f1[0] * QSCALE, f1[1] * QSCALE);
            w[3] = pack2bf(f1[2] * QSCALE, f1[3] * QSCALE);
            qf[ks] = __builtin_bit_cast(short8, w);
        }
    }

    // O^T accumulators: lane q = l31, d = dblk*32 + (r&3) + 8*(r>>2) + 4*hi
    f32x16 oacc[4];
    #pragma unroll
    for (int dblk = 0; dblk < 4; ++dblk)
        #pragma unroll
        for (int i = 0; i < 16; ++i)
            oacc[dblk][i] = 0.f;

    float mrun = -INFINITY;   // log2 units, shared across halves
    float lrun = 0.f;         // per-half partial; merged in epilogue

    int lo = ctx + q0 - WINDOW + 1; if (lo < 0) lo = 0;
    int hiq = ctx + q0 + QB - 1;    if (hiq > slen - 1) hiq = slen - 1;
    const int t0 = lo / KVB, t1 = hiq / KVB;

    // staging maps (128 threads stage 32 kv x 128 d, K + V)
    const int srow = tid >> 2;          // K: kv row 0..31
    const int sd0  = (tid & 3) * 32;    // K: d offset (f32/short idx: 0/32/64/96)
    const int j4   = tid & 7;           // V: kv quad (rows 4j4..4j4+3)
    const int d0v  = (tid >> 3) * 8;    // V: d offset (0..120)

    floatx4 fk[8], fv[8];               // raw f32 for next tile

#define LOAD_K(kv0_) {                                                               \
        const int kvp = (kv0_) + srow;                                               \
        const int blk = bt[s * NBLK_PER_SEQ + (kvp >> 4)];                           \
        const float* src = kg + (((size_t)blk * BLKSZ + (kvp & 15)) * HKVN + h) * HD + sd0; \
        fk[0] = *(const floatx4*)(src);        fk[1] = *(const floatx4*)(src + 4);   \
        fk[2] = *(const floatx4*)(src + 8);    fk[3] = *(const floatx4*)(src + 12);  \
        fk[4] = *(const floatx4*)(src + 16);   fk[5] = *(const floatx4*)(src + 20);  \
        fk[6] = *(const floatx4*)(src + 24);   fk[7] = *(const floatx4*)(src + 28);  \
    }
#define LOAD_V(kv0_) {                                                               \
        const int kvv = (kv0_) + 4 * j4;                                             \
        const int blkv = bt[s * NBLK_PER_SEQ + (kvv >> 4)];                          \
        const float* vsrc = vg + (((size_t)blkv * BLKSZ + (kvv & 15)) * HKVN + h) * HD + d0v; \
        fv[0] = *(const floatx4*)(vsrc);                                             \
        fv[4] = *(const floatx4*)(vsrc + 4);                                         \
        fv[1] = *(const floatx4*)(vsrc + 1024);                                      \
        fv[5] = *(const floatx4*)(vsrc + 1028);                                      \
        fv[2] = *(const floatx4*)(vsrc + 2048);                                      \
        fv[6] = *(const floatx4*)(vsrc + 2052);                                      \
        fv[3] = *(const floatx4*)(vsrc + 3072);                                      \
        fv[7] = *(const floatx4*)(vsrc + 3076);                                      \
    }
#define LOAD_TILE(kv0_) { LOAD_K(kv0_); LOAD_V(kv0_); }

    LOAD_TILE(t0 * KVB);

    for (int t = t0; t <= t1; ++t) {
        const int kv0 = t * KVB;
        const int vb  = t & 1;

        // ---- convert + store tile t into buf[vb] (K 4xb128, V 8xb64) ----
        {
            uint4v w;
            w[0] = pack2bf(fk[0][0], fk[0][1]); w[1] = pack2bf(fk[0][2], fk[0][3]);
            w[2] = pack2bf(fk[1][0], fk[1][1]); w[3] = pack2bf(fk[1][2], fk[1][3]);
            *(uint4v*)&Klds[vb][srow][sd0] = w;
            w[0] = pack2bf(fk[2][0], fk[2][1]); w[1] = pack2bf(fk[2][2], fk[2][3]);
            w[2] = pack2bf(fk[3][0], fk[3][1]); w[3] = pack2bf(fk[3][2], fk[3][3]);
            *(uint4v*)&Klds[vb][srow][sd0 + 8] = w;
            w[0] = pack2bf(fk[4][0], fk[4][1]); w[1] = pack2bf(fk[4][2], fk[4][3]);
            w[2] = pack2bf(fk[5][0], fk[5][1]); w[3] = pack2bf(fk[5][2], fk[5][3]);
            *(uint4v*)&Klds[vb][srow][sd0 + 16] = w;
            w[0] = pack2bf(fk[6][0], fk[6][1]); w[1] = pack2bf(fk[6][2], fk[6][3]);
            w[2] = pack2bf(fk[7][0], fk[7][1]); w[3] = pack2bf(fk[7][2], fk[7][3]);
            *(uint4v*)&Klds[vb][srow][sd0 + 24] = w;
        }
        #pragma unroll
        for (int d = 0; d < 8; ++d) {
            const float r0 = (d < 4) ? fv[0][d] : fv[4][d - 4];
            const float r1 = (d < 4) ? fv[1][d] : fv[5][d - 4];
            const float r2 = (d < 4) ? fv[2][d] : fv[6][d - 4];
            const float r3 = (d < 4) ? fv[3][d] : fv[7][d - 4];
            uint2v w;
            w[0] = pack2bf(r0, r1);   // kv 4j4, 4j4+1
            w[1] = pack2bf(r2, r3);   // kv 4j4+2, 4j4+3
            *(uint2v*)&Vt[vb][d0v + d][4 * j4] = w;
        }

        __syncthreads();   // single barrier: buf[vb] visible; buf[vb^1] readers
                           // (tile t-1 compute) finished before this barrier

        // ---- swapped QK^T 32x32: S^T[kv][q] = mfma32(A=K, B=Q) ----
        f32x16 sacc;
        #pragma unroll
        for (int i = 0; i < 16; ++i) sacc[i] = 0.f;
        #pragma unroll
        for (int ks = 0; ks < 8; ++ks) {
            short8 kf = *(const short8*)&Klds[vb][l31][ks * 16 + hi * 8];
            sacc = MFMA32(kf, qf[ks], sacc, 0, 0, 0);
        }

        // ---- issue next tile's loads: no barrier before consumption ----
        if (t < t1) LOAD_TILE(kv0 + KVB);

        // ---- lane-local online softmax over 32 kv (exp2 domain) ----
        const bool interior = (kv0 >= ctx + q0 - (WINDOW - QB)) &&
                              (kv0 + KVB - 1 <= ctx + q0);
        const int qpos = ctx + q0 + l31;
        float p[16];
        #pragma unroll
        for (int r = 0; r < 16; ++r) {
            float x = sacc[r];
            if (!interior) {
                const int kpos = kv0 + (r & 3) + 4 * hi + 8 * (r >> 2);
                const bool valid = (kpos <= qpos) && (qpos - kpos < WINDOW);
                x = valid ? x : -INFINITY;
            }
            p[r] = x;
        }
        // balanced-tree max (depth 4)
        float tmax[8];
        #pragma unroll
        for (int r = 0; r < 8; ++r) tmax[r] = fmaxf(p[r], p[r + 8]);
        #pragma unroll
        for (int s2 = 4; s2 > 0; s2 >>= 1)
            #pragma unroll
            for (int r = 0; r < 4; ++r)
                if (r < s2) tmax[r] = fmaxf(tmax[r], tmax[r + s2]);
        float rmax = xhalf_max(tmax[0]);

        const float mold = mrun;
        const bool defer = __all(rmax <= mold + 11.0f);
        const float mnew = defer ? mold : fmaxf(mold, rmax);
        const float alpha = defer ? 1.0f
            : ((mold == -INFINITY) ? ((mnew == -INFINITY) ? 1.0f : 0.0f)
                                   : exp2f(mold - mnew));
        const bool dead = (mnew == -INFINITY);
        #pragma unroll
        for (int r = 0; r < 16; ++r)
            p[r] = dead ? 0.f : exp2f(p[r] - mnew);
        // balanced-tree sum; lrun per-half (merged in epilogue)
        float ts[8];
        #pragma unroll
        for (int r = 0; r < 8; ++r) ts[r] = p[r] + p[r + 8];
        #pragma unroll
        for (int s2 = 4; s2 > 0; s2 >>= 1)
            #pragma unroll
            for (int r = 0; r < 4; ++r)
                if (r < s2) ts[r] = ts[r] + ts[r + s2];
        lrun = lrun * alpha + ts[0];
        mrun = mnew;
        if (!defer) {
            #pragma unroll
            for (int dblk = 0; dblk < 4; ++dblk)
                oacc[dblk] = oacc[dblk] * alpha;
        }

        // ---- pack P -> B-frags; single-shfl cross-half exchange ----
        short8 pb0, pb1;
        {
            unsigned int c0 = pack2bf(p[0],  p[1]);
            unsigned int c1 = pack2bf(p[2],  p[3]);
            unsigned int c2 = pack2bf(p[4],  p[5]);
            unsigned int c3 = pack2bf(p[6],  p[7]);
            unsigned int c4 = pack2bf(p[8],  p[9]);
            unsigned int c5 = pack2bf(p[10], p[11]);
            unsigned int c6 = pack2bf(p[12], p[13]);
            unsigned int c7 = pack2bf(p[14], p[15]);
            unsigned int s0 = hi ? c0 : c2;
            unsigned int s1 = hi ? c1 : c3;
            unsigned int s2 = hi ? c4 : c6;
            unsigned int s3 = hi ? c5 : c7;
            unsigned int r0 = (unsigned int)__shfl_xor((int)s0, 32);
            unsigned int r1 = (unsigned int)__shfl_xor((int)s1, 32);
            unsigned int r2 = (unsigned int)__shfl_xor((int)s2, 32);
            unsigned int r3 = (unsigned int)__shfl_xor((int)s3, 32);
            uint4v u0, u1;
            u0[0] = hi ? r0 : c0;
            u0[1] = hi ? r1 : c1;
            u0[2] = hi ? c2 : r0;
            u0[3] = hi ? c3 : r1;
            u1[0] = hi ? r2 : c4;
            u1[1] = hi ? r3 : c5;
            u1[2] = hi ? c6 : r2;
            u1[3] = hi ? c7 : r3;
            pb0 = __builtin_bit_cast(short8, u0);   // kv 0..15
            pb1 = __builtin_bit_cast(short8, u1);   // kv 16..31
        }

        // ---- PV 32x32: O^T += mfma32(A=V^T, B=P^T) ----
        #pragma unroll
        for (int dblk = 0; dblk < 4; ++dblk) {
            short8 vf0 = *(const short8*)&Vt[vb][dblk * 32 + l31][hi * 8];
            short8 vf1 = *(const short8*)&Vt[vb][dblk * 32 + l31][16 + hi * 8];
            oacc[dblk] = MFMA32(vf0, pb0, oacc[dblk], 0, 0, 0);
            oacc[dblk] = MFMA32(vf1, pb1, oacc[dblk], 0, 0, 0);
        }
    }
#undef LOAD_TILE
#undef LOAD_V
#undef LOAD_K

    // ---- epilogue: merge per-half l, lane-local normalize, b128 stores ----
    {
        const float ltot = lrun + __shfl_xor(lrun, 32);
        const float inv = 1.0f / ltot;
        float* orow = outg + ((size_t)(qstart + q0 + l31) * HQN + hq) * HD;
        #pragma unroll
        for (int dblk = 0; dblk < 4; ++dblk) {
            #pragma unroll
            for (int rq = 0; rq < 4; ++rq) {
                floatx4 o;
                o[0] = oacc[dblk][4 * rq + 0] * inv;
                o[1] = oacc[dblk][4 * rq + 1] * inv;
                o[2] = oacc[dblk][4 * rq + 2] * inv;
                o[3] = oacc[dblk][4 * rq + 3] * inv;
                *(floatx4*)(orow + dblk * 32 + 8 * rq + 4 * hi) = o;
            }
        }
    }
}

extern "C" void kernel_launch(void* const* d_in, const int* in_sizes, int n_in,
                              void* d_out, int out_size, void* d_ws, size_t ws_size,
                              hipStream_t stream) {
    const float* q  = (const float*)d_in[0];
    const float* k  = (const float*)d_in[1];
    const float* v  = (const float*)d_in[2];
    const int* btp  = (const int*)d_in[3];
    const int* sl   = (const int*)d_in[4];
    const int* qs   = (const int*)d_in[5];
    float* out      = (float*)d_out;

    attn_fwd<<<dim3(NSEQ * HKVN * 8 * 2), 128, 0, stream>>>(q, k, v, btp, sl, qs, out);
}

// Round 22
// 78.706 us; speedup vs baseline: 1.7783x; 1.7783x over previous
//
#include <hip/hip_runtime.h>
#include <stdint.h>

typedef __attribute__((ext_vector_type(8))) short short8;
typedef __attribute__((ext_vector_type(4))) float floatx4;
typedef __attribute__((ext_vector_type(16))) float f32x16;
typedef __attribute__((ext_vector_type(4))) unsigned int uint4v;
typedef __attribute__((ext_vector_type(2))) unsigned int uint2v;

#define NSEQ 8
#define BLKSZ 16
#define NBLK_PER_SEQ 128
#define HQN 32
#define HKVN 8
#define GQ 4
#define HD 128
#define WINDOW 1024
// SCALE * log2(e): softmax in exp2 domain
#define QSCALE 0.12751744f

#define QB 32       // q rows per block (4 waves = 4 GQA heads share K/V)
#define KVB 64      // kv tile (K and V both double-buffered -> 1 barrier/tile)
#define KROW 136    // K lds row stride (bf16)
#define VROW 72     // V^T lds row stride

#define MFMA32 __builtin_amdgcn_mfma_f32_32x32x16_bf16

// two f32 -> packed bf16x2 (round-half-up); low16 = lo, high16 = hi
static __device__ __forceinline__ unsigned int pack2bf(float lo, float hi) {
    unsigned int a = __builtin_bit_cast(unsigned int, lo) + 0x8000u;
    unsigned int b = __builtin_bit_cast(unsigned int, hi) + 0x8000u;
    return __builtin_amdgcn_perm(b, a, 0x07060302u);
}

static __device__ __forceinline__ float xhalf_max(float x) {
    return fmaxf(x, __shfl_xor(x, 32));
}

extern __shared__ char smem[];   // 71680 B: K[2][64][136] | V^T[2][128][72]

__global__ __launch_bounds__(256, 2)
void attn_fwd(const float* __restrict__ qg,
              const float* __restrict__ kg,
              const float* __restrict__ vg,
              const int* __restrict__ bt,
              const int* __restrict__ seqlens,
              const int* __restrict__ qsl,
              float* __restrict__ outg)
{
    short (*Klds)[KVB][KROW] = (short(*)[KVB][KROW])smem;            // 2 x 17408 B
    short (*Vt)[HD][VROW]    = (short(*)[HD][VROW])(smem + 34816);   // 2 x 18432 B

    const int tid  = threadIdx.x;
    const int lane = tid & 63;
    const int wave = tid >> 6;
    const int l31  = lane & 31;
    const int hi   = lane >> 5;

    // XCD pinning: consecutive block ids round-robin XCDs -> b&7 = kv head
    const int b  = blockIdx.x;
    const int h  = b & 7;
    const int qt = (b >> 3) & 7;
    const int s  = b >> 6;
    const int q0 = qt * QB;

    const int qstart = qsl[s];
    const int numq   = qsl[s + 1] - qstart;
    const int slen   = seqlens[s];
    const int ctx    = slen - numq;
    const int hq     = h * GQ + wave;

    // ---- Q fragments (B-operand 32x32x16: col=q=l31, k=ks*16+hi*8+j), pre-scaled ----
    short8 qf[8];
    {
        const float* qrow = qg + ((size_t)(qstart + q0 + l31) * HQN + hq) * HD;
        #pragma unroll
        for (int ks = 0; ks < 8; ++ks) {
            floatx4 f0 = *(const floatx4*)(qrow + ks * 16 + hi * 8);
            floatx4 f1 = *(const floatx4*)(qrow + ks * 16 + hi * 8 + 4);
            uint4v w;
            w[0] = pack2bf(f0[0] * QSCALE, f0[1] * QSCALE);
            w[1] = pack2bf(f0[2] * QSCALE, f0[3] * QSCALE);
            w[2] = pack2bf(f1[0] * QSCALE, f1[1] * QSCALE);
            w[3] = pack2bf(f1[2] * QSCALE, f1[3] * QSCALE);
            qf[ks] = __builtin_bit_cast(short8, w);
        }
    }

    // O^T accumulators: lane q = l31, d = dblk*32 + (r&3) + 8*(r>>2) + 4*hi
    f32x16 oacc[4];
    #pragma unroll
    for (int dblk = 0; dblk < 4; ++dblk)
        #pragma unroll
        for (int i = 0; i < 16; ++i)
            oacc[dblk][i] = 0.f;

    float mrun = -INFINITY;   // log2 units, shared across halves
    float lrun = 0.f;         // per-half partial; merged in epilogue

    int lo = ctx + q0 - WINDOW + 1; if (lo < 0) lo = 0;
    int hiq = ctx + q0 + QB - 1;    if (hiq > slen - 1) hiq = slen - 1;
    const int t0 = lo / KVB, t1 = hiq / KVB;

    // staging maps
    const int srow = tid >> 3;          // K: kv row 0..31 (+32 for p=1)
    const int sd0  = (tid & 7) * 16;    // K: d offset (floats)
    const int j4   = tid & 15;          // V: kv quad index (rows 4j4..4j4+3)
    const int d0v  = (tid >> 4) * 8;    // V: d offset (0..120)

    floatx4 fk[8], fv[8];               // raw f32 for next tile

#define LOAD_K_HALF(kv0_, p) {                                                       \
        const int kvp = (kv0_) + (p) * 32 + srow;                                    \
        const int blk = bt[s * NBLK_PER_SEQ + (kvp >> 4)];                           \
        const float* src = kg + (((size_t)blk * BLKSZ + (kvp & 15)) * HKVN + h) * HD + sd0; \
        fk[(p)*4+0] = *(const floatx4*)(src);                                        \
        fk[(p)*4+1] = *(const floatx4*)(src + 4);                                    \
        fk[(p)*4+2] = *(const floatx4*)(src + 8);                                    \
        fk[(p)*4+3] = *(const floatx4*)(src + 12);                                   \
    }
#define LOAD_V(kv0_) {                                                               \
        const int kvv = (kv0_) + 4 * j4;                                             \
        const int blkv = bt[s * NBLK_PER_SEQ + (kvv >> 4)];                          \
        const float* vsrc = vg + (((size_t)blkv * BLKSZ + (kvv & 15)) * HKVN + h) * HD + d0v; \
        fv[0] = *(const floatx4*)(vsrc);                                             \
        fv[4] = *(const floatx4*)(vsrc + 4);                                         \
        fv[1] = *(const floatx4*)(vsrc + 1024);                                      \
        fv[5] = *(const floatx4*)(vsrc + 1028);                                      \
        fv[2] = *(const floatx4*)(vsrc + 2048);                                      \
        fv[6] = *(const floatx4*)(vsrc + 2052);                                      \
        fv[3] = *(const floatx4*)(vsrc + 3072);                                      \
        fv[7] = *(const floatx4*)(vsrc + 3076);                                      \
    }
#define LOAD_TILE(kv0_) { LOAD_K_HALF(kv0_, 0); LOAD_K_HALF(kv0_, 1); LOAD_V(kv0_); }

    LOAD_TILE(t0 * KVB);

    for (int t = t0; t <= t1; ++t) {
        const int kv0 = t * KVB;
        const int vb  = t & 1;

        // ---- convert + store tile t into buf[vb] (K 2x2 b128, V 8x b64) ----
        // Overwrites parity-vb buffers last read by iter t-2, ordered by bar(t-1).
        #pragma unroll
        for (int p = 0; p < 2; ++p) {
            const int row = p * 32 + srow;
            uint4v w;
            w[0] = pack2bf(fk[p*4+0][0], fk[p*4+0][1]);
            w[1] = pack2bf(fk[p*4+0][2], fk[p*4+0][3]);
            w[2] = pack2bf(fk[p*4+1][0], fk[p*4+1][1]);
            w[3] = pack2bf(fk[p*4+1][2], fk[p*4+1][3]);
            *(uint4v*)&Klds[vb][row][sd0] = w;
            w[0] = pack2bf(fk[p*4+2][0], fk[p*4+2][1]);
            w[1] = pack2bf(fk[p*4+2][2], fk[p*4+2][3]);
            w[2] = pack2bf(fk[p*4+3][0], fk[p*4+3][1]);
            w[3] = pack2bf(fk[p*4+3][2], fk[p*4+3][3]);
            *(uint4v*)&Klds[vb][row][sd0 + 8] = w;
        }
        #pragma unroll
        for (int d = 0; d < 8; ++d) {
            const float r0 = (d < 4) ? fv[0][d] : fv[4][d - 4];
            const float r1 = (d < 4) ? fv[1][d] : fv[5][d - 4];
            const float r2 = (d < 4) ? fv[2][d] : fv[6][d - 4];
            const float r3 = (d < 4) ? fv[3][d] : fv[7][d - 4];
            uint2v w;
            w[0] = pack2bf(r0, r1);   // kv 4j4, 4j4+1
            w[1] = pack2bf(r2, r3);   // kv 4j4+2, 4j4+3
            *(uint2v*)&Vt[vb][d0v + d][4 * j4] = w;
        }

        __syncthreads();   // SINGLE barrier per tile: buf[vb] visible; protects
                           // same-parity reuse (iter t+2) transitively

        // ---- swapped QK^T 32x32 on both kv-halves ----
        f32x16 sacc0, sacc1;
        #pragma unroll
        for (int i = 0; i < 16; ++i) { sacc0[i] = 0.f; sacc1[i] = 0.f; }
        #pragma unroll
        for (int ks = 0; ks < 8; ++ks) {
            short8 kf0 = *(const short8*)&Klds[vb][l31][ks * 16 + hi * 8];
            short8 kf1 = *(const short8*)&Klds[vb][32 + l31][ks * 16 + hi * 8];
            sacc0 = MFMA32(kf0, qf[ks], sacc0, 0, 0, 0);
            sacc1 = MFMA32(kf1, qf[ks], sacc1, 0, 0, 0);
        }

        // ---- issue next tile's loads: consumed at next loop-top stores,
        //      no barrier crosses the in-flight window ----
        if (t < t1) LOAD_TILE(kv0 + KVB);

        // ---- lane-local online softmax over 64 kv (exp2 domain) ----
        const bool interior = (kv0 >= ctx + q0 - (WINDOW - QB)) &&
                              (kv0 + KVB - 1 <= ctx + q0);
        const int qpos = ctx + q0 + l31;
        float p2[2][16];
        #pragma unroll
        for (int m2 = 0; m2 < 2; ++m2) {
            #pragma unroll
            for (int r = 0; r < 16; ++r) {
                float x = (m2 == 0) ? sacc0[r] : sacc1[r];
                if (!interior) {
                    const int kpos = kv0 + m2 * 32 + (r & 3) + 4 * hi + 8 * (r >> 2);
                    const bool valid = (kpos <= qpos) && (qpos - kpos < WINDOW);
                    x = valid ? x : -INFINITY;
                }
                p2[m2][r] = x;
            }
        }
        // balanced-tree max (depth 5)
        float tmax[16];
        #pragma unroll
        for (int r = 0; r < 16; ++r) tmax[r] = fmaxf(p2[0][r], p2[1][r]);
        #pragma unroll
        for (int s2 = 8; s2 > 0; s2 >>= 1)
            #pragma unroll
            for (int r = 0; r < 8; ++r)
                if (r < s2) tmax[r] = fmaxf(tmax[r], tmax[r + s2]);
        float rmax = xhalf_max(tmax[0]);

        const float mold = mrun;
        const bool defer = __all(rmax <= mold + 11.0f);   // THR ~ 8 nats in log2
        const float mnew = defer ? mold : fmaxf(mold, rmax);
        const float alpha = defer ? 1.0f
            : ((mold == -INFINITY) ? ((mnew == -INFINITY) ? 1.0f : 0.0f)
                                   : exp2f(mold - mnew));
        const bool dead = (mnew == -INFINITY);
        #pragma unroll
        for (int m2 = 0; m2 < 2; ++m2)
            #pragma unroll
            for (int r = 0; r < 16; ++r)
                p2[m2][r] = dead ? 0.f : exp2f(p2[m2][r] - mnew);
        // balanced-tree sum; lrun per-half (merged in epilogue)
        float ts[16];
        #pragma unroll
        for (int r = 0; r < 16; ++r) ts[r] = p2[0][r] + p2[1][r];
        #pragma unroll
        for (int s2 = 8; s2 > 0; s2 >>= 1)
            #pragma unroll
            for (int r = 0; r < 8; ++r)
                if (r < s2) ts[r] = ts[r] + ts[r + s2];
        lrun = lrun * alpha + ts[0];
        mrun = mnew;
        if (!defer) {
            #pragma unroll
            for (int dblk = 0; dblk < 4; ++dblk)
                oacc[dblk] = oacc[dblk] * alpha;
        }

        // ---- pack P -> B-frags; pre-selected single-shfl cross-half exchange ----
        short8 pb[2][2];
        #pragma unroll
        for (int m2 = 0; m2 < 2; ++m2) {
            unsigned int c0 = pack2bf(p2[m2][0],  p2[m2][1]);
            unsigned int c1 = pack2bf(p2[m2][2],  p2[m2][3]);
            unsigned int c2 = pack2bf(p2[m2][4],  p2[m2][5]);
            unsigned int c3 = pack2bf(p2[m2][6],  p2[m2][7]);
            unsigned int c4 = pack2bf(p2[m2][8],  p2[m2][9]);
            unsigned int c5 = pack2bf(p2[m2][10], p2[m2][11]);
            unsigned int c6 = pack2bf(p2[m2][12], p2[m2][13]);
            unsigned int c7 = pack2bf(p2[m2][14], p2[m2][15]);
            unsigned int s0 = hi ? c0 : c2;
            unsigned int s1 = hi ? c1 : c3;
            unsigned int s2 = hi ? c4 : c6;
            unsigned int s3 = hi ? c5 : c7;
            unsigned int r0 = (unsigned int)__shfl_xor((int)s0, 32);
            unsigned int r1 = (unsigned int)__shfl_xor((int)s1, 32);
            unsigned int r2 = (unsigned int)__shfl_xor((int)s2, 32);
            unsigned int r3 = (unsigned int)__shfl_xor((int)s3, 32);
            uint4v u0, u1;
            u0[0] = hi ? r0 : c0;
            u0[1] = hi ? r1 : c1;
            u0[2] = hi ? c2 : r0;
            u0[3] = hi ? c3 : r1;
            u1[0] = hi ? r2 : c4;
            u1[1] = hi ? r3 : c5;
            u1[2] = hi ? c6 : r2;
            u1[3] = hi ? c7 : r3;
            pb[m2][0] = __builtin_bit_cast(short8, u0);   // kv m2*32 + 0..15
            pb[m2][1] = __builtin_bit_cast(short8, u1);   // kv m2*32 + 16..31
        }

        // ---- PV 32x32: O^T += mfma32(A=V^T, B=P^T), both kv-halves ----
        #pragma unroll
        for (int m2 = 0; m2 < 2; ++m2) {
            #pragma unroll
            for (int dblk = 0; dblk < 4; ++dblk) {
                short8 vf0 = *(const short8*)&Vt[vb][dblk * 32 + l31][m2 * 32 + hi * 8];
                short8 vf1 = *(const short8*)&Vt[vb][dblk * 32 + l31][m2 * 32 + 16 + hi * 8];
                oacc[dblk] = MFMA32(vf0, pb[m2][0], oacc[dblk], 0, 0, 0);
                oacc[dblk] = MFMA32(vf1, pb[m2][1], oacc[dblk], 0, 0, 0);
            }
        }
    }
#undef LOAD_TILE
#undef LOAD_V
#undef LOAD_K_HALF

    // ---- epilogue: merge per-half l, lane-local normalize, b128 stores ----
    {
        const float ltot = lrun + __shfl_xor(lrun, 32);
        const float inv = 1.0f / ltot;
        float* orow = outg + ((size_t)(qstart + q0 + l31) * HQN + hq) * HD;
        #pragma unroll
        for (int dblk = 0; dblk < 4; ++dblk) {
            #pragma unroll
            for (int rq = 0; rq < 4; ++rq) {
                floatx4 o;
                o[0] = oacc[dblk][4 * rq + 0] * inv;
                o[1] = oacc[dblk][4 * rq + 1] * inv;
                o[2] = oacc[dblk][4 * rq + 2] * inv;
                o[3] = oacc[dblk][4 * rq + 3] * inv;
                *(floatx4*)(orow + dblk * 32 + 8 * rq + 4 * hi) = o;
            }
        }
    }
}

extern "C" void kernel_launch(void* const* d_in, const int* in_sizes, int n_in,
                              void* d_out, int out_size, void* d_ws, size_t ws_size,
                              hipStream_t stream) {
    const float* q  = (const float*)d_in[0];
    const float* k  = (const float*)d_in[1];
    const float* v  = (const float*)d_in[2];
    const int* btp  = (const int*)d_in[3];
    const int* sl   = (const int*)d_in[4];
    const int* qs   = (const int*)d_in[5];
    float* out      = (float*)d_out;

    hipFuncSetAttribute((const void*)attn_fwd,
                        hipFuncAttributeMaxDynamicSharedMemorySize, 71680);
    attn_fwd<<<dim3(NSEQ * HKVN * 8), 256, 71680, stream>>>(q, k, v, btp, sl, qs, out);
}